// Round 10
// baseline (443.563 us; speedup 1.0000x reference)
//
#include <hip/hip_runtime.h>
#include <hip/hip_bf16.h>

#define SEQ   128
#define BATCH 64
#define EMB   128
#define CELL  128
#define VOCAB 10000
#define NPADV 10240          // vocab rows padded to /64
#define ROWS  8192           // SEQ*BATCH
#define GATES 512            // 4*CELL
#define INDIM 256            // EMB+CELL (gate weight row stride)

typedef short  short8 __attribute__((ext_vector_type(8)));
typedef float  f32x4  __attribute__((ext_vector_type(4)));
typedef unsigned short u16;

static __device__ __forceinline__ u16 f2bf(float f) {
  union { float f; unsigned int u; } v; v.f = f;
  unsigned int u = v.u;
  return (u16)((u + 0x7fffu + ((u >> 16) & 1u)) >> 16);   // RNE
}
static __device__ __forceinline__ float fexp(float x) {
  return __builtin_amdgcn_exp2f(x * 1.44269504088896340736f);
}
static __device__ __forceinline__ float fsig(float x) {
  return __builtin_amdgcn_rcpf(1.0f + fexp(-x));
}
static __device__ __forceinline__ float ftanh(float x) {
  float e = fexp(2.0f * x);                 // e^(2x); overflows to inf -> returns 1 (ok)
  return 1.0f - 2.0f * __builtin_amdgcn_rcpf(e + 1.0f);
}

// ================= STORE-PATH PROBES (measurement round) =================
// Each writes ~330 MB into d_out; the real pipeline runs afterwards and
// overwrites everything, so final output is still correct. They isolate the
// write path: zero loads, zero MFMA, zero barriers, max issue rate.
// Axis swept: concurrent stream count / per-stream advance pattern.

// 1 stream: single global sequential front (fill replica). 2048 blocks.
__global__ void k_probe_lin(float* __restrict__ out, int out_size) {
  int tid = blockIdx.x * blockDim.x + threadIdx.x;   // 524288 threads
  f32x4 v = {1.f, 2.f, 3.f, (float)tid};
  for (int i = 0; i < 40; ++i) {
    size_t idx = (size_t)i * 524288 + tid;           // 8.4MB front per iter
    if (idx * 4 + 3 < (size_t)out_size)
      *(f32x4*)(out + idx * 4) = v;
  }
}

// 2560 streams: each wave streams whole 40KB rows linearly, 1KB per instr.
__global__ void k_probe_row(float* __restrict__ out) {
  int lane = threadIdx.x & 63, wv = threadIdx.x >> 6;
  int wave = blockIdx.x * 4 + wv;                    // 640 blocks x 4 waves
  f32x4 v = {1.f, 2.f, 3.f, (float)lane};
  for (int r = wave; r < ROWS; r += 2560) {
    float* dst = out + (size_t)r * VOCAB;
    for (int i = 0; i < 40; ++i) {
      int off = i * 256 + lane * 4;
      if (off + 3 < VOCAB) *(f32x4*)(dst + off) = v;
    }
  }
}

// 32768 streams: v3's exact scatter (16 rows x 64B per store instr). 1024 blocks.
__global__ void k_probe_sc(float* __restrict__ out) {
  int tid = threadIdx.x;
  int lane = tid & 63, wv = tid >> 6;
  int lr = lane & 15, kh = lane >> 4;
  int band  = blockIdx.x >> 2;
  int slice = blockIdx.x & 3;
  int rowbase = band * 32;
  int colbase = slice * 2560 + wv * 640;
  f32x4 v = {1.f, 2.f, 3.f, (float)lane};
  for (int g = 0; g < 40; ++g) {
    int colg = colbase + g * 16;
    if (colg < VOCAB) {
      int c = colg + kh * 4;
      *(f32x4*)(out + (size_t)(rowbase + lr) * VOCAB + c) = v;
      *(f32x4*)(out + (size_t)(rowbase + 16 + lr) * VOCAB + c) = v;
    }
  }
}

// ---------- prep kernels ----------
__global__ void k_convert_W(const float* __restrict__ W, u16* __restrict__ Wbf) {
  int idx = blockIdx.x * blockDim.x + threadIdx.x;
  if (idx >= NPADV * EMB) return;
  int v = idx >> 7, k = idx & 127;
  float val = (v < VOCAB) ? W[(size_t)v * EMB + k] : 0.f;
  Wbf[idx] = f2bf(val);
}

__global__ void k_build_gates(const float* __restrict__ Wc, const float* __restrict__ Bc,
                              const float* __restrict__ Wf, const float* __restrict__ Bf,
                              const float* __restrict__ Wi, const float* __restrict__ Bi,
                              const float* __restrict__ Wo, const float* __restrict__ Bo,
                              u16* __restrict__ Wall, float* __restrict__ Ball) {
  int idx = blockIdx.x * blockDim.x + threadIdx.x;
  if (idx < GATES * EMB) {
    int r = idx >> 7, k = idx & 127;
    int g = r >> 7, j = r & 127;
    const float* Wg = (g == 0) ? Wc : (g == 1) ? Wf : (g == 2) ? Wi : Wo;
    Wall[idx] = f2bf(Wg[(size_t)j * INDIM + k]);          // embedding-part columns 0..127
  }
  if (idx < GATES) {
    int g = idx >> 7, j = idx & 127;
    const float* Bg = (g == 0) ? Bc : (g == 1) ? Bf : (g == 2) ? Bi : Bo;
    Ball[idx] = Bg[j];
  }
}

__global__ void k_gather_xe(const int* __restrict__ x, const float* __restrict__ emb,
                            u16* __restrict__ Xe) {
  int idx = blockIdx.x * blockDim.x + threadIdx.x;
  if (idx >= ROWS * EMB) return;
  int c = idx >> 7, e = idx & 127;
  int tok = x[c];                                         // x is [SEQ][BATCH], c = t*64+b
  Xe[idx] = f2bf(emb[(size_t)tok * EMB + e]);
}

// ---------- small bf16 MFMA GEMM (Zin): out[row][col] = A[row]·B[col] + bias[col] ----------
__launch_bounds__(256)
__global__ void k_gemm(const u16* __restrict__ A, const u16* __restrict__ B,
                       const float* __restrict__ bias, float* __restrict__ out,
                       int Nout) {
  __shared__ float tile[64][68];
  int lane = threadIdx.x & 63;
  int wave = threadIdx.x >> 6;
  int lr = lane & 15;
  int kh = lane >> 4;
  int rowbase = blockIdx.y * 64;
  int colblk  = blockIdx.x * 64;
  int colbase = colblk + wave * 16;

  const short8* A8 = (const short8*)A;
  const short8* B8 = (const short8*)B;

  f32x4 acc[4] = {};
#pragma unroll
  for (int ks = 0; ks < 4; ++ks) {
    short8 bfrag = B8[(size_t)(colbase + lr) * 16 + ks * 4 + kh];
#pragma unroll
    for (int m = 0; m < 4; ++m) {
      short8 afrag = A8[(size_t)(rowbase + m * 16 + lr) * 16 + ks * 4 + kh];
      acc[m] = __builtin_amdgcn_mfma_f32_16x16x32_bf16(afrag, bfrag, acc[m], 0, 0, 0);
    }
  }

#pragma unroll
  for (int m = 0; m < 4; ++m)
#pragma unroll
    for (int q = 0; q < 4; ++q)
      tile[m * 16 + kh * 4 + q][wave * 16 + lr] = acc[m][q];
  __syncthreads();

  int col4 = lane & 15;
  int c = colblk + col4 * 4;
  if (c < Nout) {
    f32x4 bv = {};
    if (bias) bv = *(const f32x4*)(bias + c);
#pragma unroll
    for (int i = 0; i < 4; ++i) {
      int r = wave * 16 + i * 4 + (lane >> 4);
      f32x4 v = *(const f32x4*)(&tile[r][col4 * 4]);
      v += bv;
      *(f32x4*)(out + (size_t)(rowbase + r) * Nout + c) = v;
    }
  }
}

// ---------- vocab projection v3: operand-swapped MFMA, register-direct stores ----------
// (round-5 best: ~145us, 2.2 TB/s writes)
__launch_bounds__(256, 4)
__global__ void k_vocab3(const u16* __restrict__ A, const u16* __restrict__ B,
                         const float* __restrict__ bias, float* __restrict__ out) {
  int tid = threadIdx.x;
  int lane = tid & 63, wv = tid >> 6;
  int lr = lane & 15, kh = lane >> 4;
  int band  = blockIdx.x >> 2;            // 256 bands of 32 rows
  int slice = blockIdx.x & 3;             // 4 col-slices of 2560
  int rowbase = band * 32;
  int colbase = slice * 2560 + wv * 640;  // this wave: 40 groups of 16 cols

  const short8* A8 = (const short8*)A;
  const short8* B8 = (const short8*)B;

  short8 af0[4], af1[4];
#pragma unroll
  for (int ks = 0; ks < 4; ++ks) {
    af0[ks] = A8[(size_t)(rowbase + lr) * 16 + ks * 4 + kh];
    af1[ks] = A8[(size_t)(rowbase + 16 + lr) * 16 + ks * 4 + kh];
  }

  short8 vf[2][4];
  f32x4 bv[2];
#pragma unroll
  for (int ks = 0; ks < 4; ++ks)
    vf[0][ks] = B8[(size_t)(colbase + lr) * 16 + ks * 4 + kh];
  bv[0] = *(const f32x4*)(bias + colbase + kh * 4);

  for (int g = 0; g < 40; ++g) {
    int cur = g & 1, nxt = cur ^ 1;
    if (g + 1 < 40) {
      int cg = colbase + (g + 1) * 16;
#pragma unroll
      for (int ks = 0; ks < 4; ++ks)
        vf[nxt][ks] = B8[(size_t)(cg + lr) * 16 + ks * 4 + kh];
      bv[nxt] = *(const f32x4*)(bias + cg + kh * 4);
    }

    f32x4 a0 = {}, a1 = {};
#pragma unroll
    for (int ks = 0; ks < 4; ++ks) {
      a0 = __builtin_amdgcn_mfma_f32_16x16x32_bf16(vf[cur][ks], af0[ks], a0, 0, 0, 0);
      a1 = __builtin_amdgcn_mfma_f32_16x16x32_bf16(vf[cur][ks], af1[ks], a1, 0, 0, 0);
    }

    int colg = colbase + g * 16;
    if (colg < VOCAB) {                   // VOCAB%16==0: whole group valid or not
      int c = colg + kh * 4;
      a0 += bv[cur];
      a1 += bv[cur];
      *(f32x4*)(out + (size_t)(rowbase + lr) * VOCAB + c) = a0;
      *(f32x4*)(out + (size_t)(rowbase + 16 + lr) * VOCAB + c) = a1;
    }
  }
}

// ---------- sequential LSTM recurrence: one workgroup per batch column ----------
__launch_bounds__(512, 2)
__global__ void k_recur(const float* __restrict__ Wc, const float* __restrict__ Wf,
                        const float* __restrict__ Wi, const float* __restrict__ Wo,
                        const float* __restrict__ Zin, u16* __restrict__ Hbf,
                        float* __restrict__ outHC) {
  __shared__ float Hl[CELL];
  __shared__ float zl[GATES];
  int tid = threadIdx.x;
  int b = blockIdx.x;
  int lane = tid & 63;
  int g = tid >> 7, j = tid & 127;
  const float* Wg = (g == 0) ? Wc : (g == 1) ? Wf : (g == 2) ? Wi : Wo;
  const float* wp = Wg + (size_t)j * INDIM + EMB;

  float w[128];
#pragma unroll
  for (int k = 0; k < 128; ++k) w[k] = wp[k];

  if (tid < CELL) Hl[tid] = 0.f;
  float C = 0.f;

  // rolling depth-2 Zin prefetch
  float zcur = Zin[(size_t)(0 * BATCH + b) * GATES + tid];
  float znxt = Zin[(size_t)(1 * BATCH + b) * GATES + tid];
  __syncthreads();

  for (int t = 0; t < SEQ; ++t) {
    float zv = zcur;
    zcur = znxt;
    if (t + 2 < SEQ)
      znxt = Zin[(size_t)((t + 2) * BATCH + b) * GATES + tid];

    float h0 = Hl[lane];
    float h1 = Hl[lane + 64];
    float a0 = 0.f, a1 = 0.f, a2 = 0.f, a3 = 0.f;
#pragma unroll
    for (int k = 0; k < 32; ++k) {
      float p0 = __uint_as_float(__builtin_amdgcn_readlane(__float_as_uint(h0), k));
      a0 += w[k] * p0;
      float p1 = __uint_as_float(__builtin_amdgcn_readlane(__float_as_uint(h0), k + 32));
      a1 += w[k + 32] * p1;
      float p2 = __uint_as_float(__builtin_amdgcn_readlane(__float_as_uint(h1), k));
      a2 += w[k + 64] * p2;
      float p3 = __uint_as_float(__builtin_amdgcn_readlane(__float_as_uint(h1), k + 32));
      a3 += w[k + 96] * p3;
    }
    zl[tid] = zv + (a0 + a1) + (a2 + a3);
    __syncthreads();
    int c = t * BATCH + b;
    if (tid < CELL) {
      float cand = ftanh(zl[tid]);
      float F = fsig(zl[CELL + tid]);
      float I = fsig(zl[2 * CELL + tid]);
      float O = fsig(zl[3 * CELL + tid]);
      C = F * C + I * cand;
      float H = ftanh(C) * O;
      Hl[tid] = H;
      Hbf[(size_t)c * CELL + tid] = f2bf(H);
      if (t == SEQ - 1) {
        outHC[(size_t)tid * BATCH + b] = H;
        outHC[(size_t)CELL * BATCH + (size_t)tid * BATCH + b] = C;
      }
    }
    __syncthreads();
  }
}

extern "C" void kernel_launch(void* const* d_in, const int* in_sizes, int n_in,
                              void* d_out, int out_size, void* d_ws, size_t ws_size,
                              hipStream_t stream) {
  const int*   x   = (const int*)d_in[0];
  const float* emb = (const float*)d_in[1];
  const float* Wc  = (const float*)d_in[2];
  const float* Bc  = (const float*)d_in[3];
  const float* Wf  = (const float*)d_in[4];
  const float* Bf  = (const float*)d_in[5];
  const float* Wi  = (const float*)d_in[6];
  const float* Bi  = (const float*)d_in[7];
  const float* Wo  = (const float*)d_in[8];
  const float* Bo  = (const float*)d_in[9];
  const float* W   = (const float*)d_in[10];
  const float* b   = (const float*)d_in[11];
  float* out = (float*)d_out;

  char* ws = (char*)d_ws;
  size_t off = 0;
  auto alloc = [&](size_t bytes) -> void* {
    void* p = ws + off;
    off = (off + bytes + 255) & ~(size_t)255;
    return p;
  };
  u16*   Wbf  = (u16*)  alloc((size_t)NPADV * EMB * 2);   // 2.56 MB
  u16*   Wall = (u16*)  alloc((size_t)GATES * EMB * 2);   // 128 KB
  float* Ball = (float*)alloc((size_t)GATES * 4);         // 2 KB
  u16*   Xe   = (u16*)  alloc((size_t)ROWS * EMB * 2);    // 2 MB
  u16*   Hbf  = (u16*)  alloc((size_t)ROWS * CELL * 2);   // 2 MB
  float* Zin  = (float*)alloc((size_t)ROWS * GATES * 4);  // 16 MB

  // ---- store-path probes (results overwritten by real pipeline below) ----
  hipLaunchKernelGGL(k_probe_lin, dim3(2048), dim3(256), 0, stream, out, out_size);
  hipLaunchKernelGGL(k_probe_row, dim3(640),  dim3(256), 0, stream, out);
  hipLaunchKernelGGL(k_probe_sc,  dim3(1024), dim3(256), 0, stream, out);

  // ---- real pipeline (byte-identical to round-7 best) ----
  hipLaunchKernelGGL(k_convert_W, dim3((NPADV * EMB + 255) / 256), dim3(256), 0, stream,
                     W, Wbf);
  hipLaunchKernelGGL(k_build_gates, dim3((GATES * EMB + 255) / 256), dim3(256), 0, stream,
                     Wc, Bc, Wf, Bf, Wi, Bi, Wo, Bo, Wall, Ball);
  hipLaunchKernelGGL(k_gather_xe, dim3((ROWS * EMB + 255) / 256), dim3(256), 0, stream,
                     x, emb, Xe);
  hipLaunchKernelGGL(k_gemm, dim3(GATES / 64, ROWS / 64), dim3(256), 0, stream,
                     Xe, Wall, Ball, Zin, GATES);
  hipLaunchKernelGGL(k_recur, dim3(BATCH), dim3(512), 0, stream,
                     Wc, Wf, Wi, Wo, Zin, Hbf, out + (size_t)ROWS * VOCAB);
  hipLaunchKernelGGL(k_vocab3, dim3(1024), dim3(256), 0, stream,
                     Hbf, Wbf, b, out);
}

// Round 11
// 340.914 us; speedup vs baseline: 1.3011x; 1.3011x over previous
//
#include <hip/hip_runtime.h>
#include <hip/hip_bf16.h>

#define SEQ   128
#define BATCH 64
#define EMB   128
#define CELL  128
#define VOCAB 10000
#define NPADV 10240          // vocab rows padded to /64
#define ROWS  8192           // SEQ*BATCH
#define GATES 512            // 4*CELL
#define INDIM 256            // EMB+CELL (gate weight row stride)

typedef short  short8 __attribute__((ext_vector_type(8)));
typedef float  f32x4  __attribute__((ext_vector_type(4)));
typedef unsigned short u16;

static __device__ __forceinline__ u16 f2bf(float f) {
  union { float f; unsigned int u; } v; v.f = f;
  unsigned int u = v.u;
  return (u16)((u + 0x7fffu + ((u >> 16) & 1u)) >> 16);   // RNE
}
static __device__ __forceinline__ float fexp(float x) {
  return __builtin_amdgcn_exp2f(x * 1.44269504088896340736f);
}
static __device__ __forceinline__ float fsig(float x) {
  return __builtin_amdgcn_rcpf(1.0f + fexp(-x));
}
static __device__ __forceinline__ float ftanh(float x) {
  float e = fexp(2.0f * x);                 // e^(2x); overflows to inf -> returns 1 (ok)
  return 1.0f - 2.0f * __builtin_amdgcn_rcpf(e + 1.0f);
}

// ---------- prep kernels ----------
__global__ void k_convert_W(const float* __restrict__ W, u16* __restrict__ Wbf,
                            const float* __restrict__ b, float* __restrict__ bpad) {
  int idx = blockIdx.x * blockDim.x + threadIdx.x;
  if (idx < NPADV) bpad[idx] = (idx < VOCAB) ? b[idx] : 0.f;   // padded bias
  if (idx >= NPADV * EMB) return;
  int v = idx >> 7, k = idx & 127;
  float val = (v < VOCAB) ? W[(size_t)v * EMB + k] : 0.f;
  Wbf[idx] = f2bf(val);
}

__global__ void k_build_gates(const float* __restrict__ Wc, const float* __restrict__ Bc,
                              const float* __restrict__ Wf, const float* __restrict__ Bf,
                              const float* __restrict__ Wi, const float* __restrict__ Bi,
                              const float* __restrict__ Wo, const float* __restrict__ Bo,
                              u16* __restrict__ Wall, float* __restrict__ Ball) {
  int idx = blockIdx.x * blockDim.x + threadIdx.x;
  if (idx < GATES * EMB) {
    int r = idx >> 7, k = idx & 127;
    int g = r >> 7, j = r & 127;
    const float* Wg = (g == 0) ? Wc : (g == 1) ? Wf : (g == 2) ? Wi : Wo;
    Wall[idx] = f2bf(Wg[(size_t)j * INDIM + k]);          // embedding-part columns 0..127
  }
  if (idx < GATES) {
    int g = idx >> 7, j = idx & 127;
    const float* Bg = (g == 0) ? Bc : (g == 1) ? Bf : (g == 2) ? Bi : Bo;
    Ball[idx] = Bg[j];
  }
}

__global__ void k_gather_xe(const int* __restrict__ x, const float* __restrict__ emb,
                            u16* __restrict__ Xe) {
  int idx = blockIdx.x * blockDim.x + threadIdx.x;
  if (idx >= ROWS * EMB) return;
  int c = idx >> 7, e = idx & 127;
  int tok = x[c];                                         // x is [SEQ][BATCH], c = t*64+b
  Xe[idx] = f2bf(emb[(size_t)tok * EMB + e]);
}

// ---------- small bf16 MFMA GEMM (Zin): out[row][col] = A[row]·B[col] + bias[col] ----------
__launch_bounds__(256)
__global__ void k_gemm(const u16* __restrict__ A, const u16* __restrict__ B,
                       const float* __restrict__ bias, float* __restrict__ out,
                       int Nout) {
  __shared__ float tile[64][68];
  int lane = threadIdx.x & 63;
  int wave = threadIdx.x >> 6;
  int lr = lane & 15;
  int kh = lane >> 4;
  int rowbase = blockIdx.y * 64;
  int colblk  = blockIdx.x * 64;
  int colbase = colblk + wave * 16;

  const short8* A8 = (const short8*)A;
  const short8* B8 = (const short8*)B;

  f32x4 acc[4] = {};
#pragma unroll
  for (int ks = 0; ks < 4; ++ks) {
    short8 bfrag = B8[(size_t)(colbase + lr) * 16 + ks * 4 + kh];
#pragma unroll
    for (int m = 0; m < 4; ++m) {
      short8 afrag = A8[(size_t)(rowbase + m * 16 + lr) * 16 + ks * 4 + kh];
      acc[m] = __builtin_amdgcn_mfma_f32_16x16x32_bf16(afrag, bfrag, acc[m], 0, 0, 0);
    }
  }

#pragma unroll
  for (int m = 0; m < 4; ++m)
#pragma unroll
    for (int q = 0; q < 4; ++q)
      tile[m * 16 + kh * 4 + q][wave * 16 + lr] = acc[m][q];
  __syncthreads();

  int col4 = lane & 15;
  int c = colblk + col4 * 4;
  if (c < Nout) {
    f32x4 bv = {};
    if (bias) bv = *(const f32x4*)(bias + c);
#pragma unroll
    for (int i = 0; i < 4; ++i) {
      int r = wave * 16 + i * 4 + (lane >> 4);
      f32x4 v = *(const f32x4*)(&tile[r][col4 * 4]);
      v += bv;
      *(f32x4*)(out + (size_t)(rowbase + r) * Nout + c) = v;
    }
  }
}

// ---------- vocab projection v7: store-wait decoupling ----------
// Probe round established: even the 64B x 16-row scatter sustains ~5 TB/s when
// stores issue freely; v3's 2.2 TB/s cap = per-wave vmcnt waits draining stores.
// Batch = 4 col-groups, double-buffered NAMED reg buffers, fully unrolled
// (all static indices). Per batch: MFMA(buf) -> bias-add -> LOAD(buf <- b+2)
// -> STORE(b). The pre-MFMA wait targets loads issued 2 batches ago, leaving
// ~8 stores + 20 loads younger in the FIFO -> stores stay in flight across
// two batch spans. No LDS, no barriers, bias pre-padded (no guarded loads).
#define LOADB(BUF, BV, BB)                                                       \
  {                                                                              \
    _Pragma("unroll")                                                            \
    for (int gi = 0; gi < 4; ++gi) {                                             \
      int gc = colbase + ((BB) * 4 + gi) * 16;                                   \
      _Pragma("unroll")                                                          \
      for (int ks = 0; ks < 4; ++ks)                                             \
        BUF[gi][ks] = B8[(size_t)(gc + lr) * 16 + ks * 4 + kh];                  \
      BV[gi] = *(const f32x4*)(bpad + gc + kh * 4);                              \
    }                                                                            \
  }

#define MFMAB(BUF)                                                               \
  {                                                                              \
    _Pragma("unroll")                                                            \
    for (int gi = 0; gi < 4; ++gi) {                                             \
      acc[gi] = f32x4{};                                                         \
      _Pragma("unroll")                                                          \
      for (int ks = 0; ks < 4; ++ks)                                             \
        acc[gi] = __builtin_amdgcn_mfma_f32_16x16x32_bf16(BUF[gi][ks], af[ks],   \
                                                          acc[gi], 0, 0, 0);     \
    }                                                                            \
  }

#define BIASADD(BV)                                                              \
  { _Pragma("unroll") for (int gi = 0; gi < 4; ++gi) acc[gi] += BV[gi]; }

#define STOREB(BB)                                                               \
  {                                                                              \
    _Pragma("unroll")                                                            \
    for (int gi = 0; gi < 4; ++gi) {                                             \
      int gc = colbase + ((BB) * 4 + gi) * 16;                                   \
      if (gc < VOCAB)                                                            \
        *(f32x4*)(out + (size_t)(rowbase + lr) * VOCAB + gc + kh * 4) = acc[gi]; \
    }                                                                            \
  }

__launch_bounds__(256, 1)
__global__ void k_vocab7(const u16* __restrict__ A, const u16* __restrict__ B,
                         const float* __restrict__ bpad, float* __restrict__ out) {
  int tid = threadIdx.x;
  int lane = tid & 63, wv = tid >> 6;     // 4 waves
  int lr = lane & 15, kh = lane >> 4;
  int band  = blockIdx.x >> 2;            // 512 bands of 16 rows
  int slice = blockIdx.x & 3;             // 4 col-slices of 2560
  int rowbase = band * 16;
  int colbase = slice * 2560 + wv * 640;  // this wave: 40 groups = 10 batches of 4

  const short8* A8 = (const short8*)A;
  const short8* B8 = (const short8*)B;

  short8 af[4];
#pragma unroll
  for (int ks = 0; ks < 4; ++ks)
    af[ks] = A8[(size_t)(rowbase + lr) * 16 + ks * 4 + kh];

  short8 bufA[4][4], bufB[4][4];
  f32x4 bvA[4], bvB[4];
  f32x4 acc[4];

  LOADB(bufA, bvA, 0)
  LOADB(bufB, bvB, 1)

#pragma unroll
  for (int b = 0; b < 10; b += 2) {
    MFMAB(bufA)
    BIASADD(bvA)
    if (b + 2 < 10) LOADB(bufA, bvA, b + 2)
    STOREB(b)

    MFMAB(bufB)
    BIASADD(bvB)
    if (b + 3 < 10) LOADB(bufB, bvB, b + 3)
    STOREB(b + 1)
  }
}

// ---------- sequential LSTM recurrence: one workgroup per batch column ----------
__launch_bounds__(512, 2)
__global__ void k_recur(const float* __restrict__ Wc, const float* __restrict__ Wf,
                        const float* __restrict__ Wi, const float* __restrict__ Wo,
                        const float* __restrict__ Zin, u16* __restrict__ Hbf,
                        float* __restrict__ outHC) {
  __shared__ float Hl[CELL];
  __shared__ float zl[GATES];
  int tid = threadIdx.x;
  int b = blockIdx.x;
  int lane = tid & 63;
  int g = tid >> 7, j = tid & 127;
  const float* Wg = (g == 0) ? Wc : (g == 1) ? Wf : (g == 2) ? Wi : Wo;
  const float* wp = Wg + (size_t)j * INDIM + EMB;

  float w[128];
#pragma unroll
  for (int k = 0; k < 128; ++k) w[k] = wp[k];

  if (tid < CELL) Hl[tid] = 0.f;
  float C = 0.f;

  // rolling depth-2 Zin prefetch
  float zcur = Zin[(size_t)(0 * BATCH + b) * GATES + tid];
  float znxt = Zin[(size_t)(1 * BATCH + b) * GATES + tid];
  __syncthreads();

  for (int t = 0; t < SEQ; ++t) {
    float zv = zcur;
    zcur = znxt;
    if (t + 2 < SEQ)
      znxt = Zin[(size_t)((t + 2) * BATCH + b) * GATES + tid];

    float h0 = Hl[lane];
    float h1 = Hl[lane + 64];
    float a0 = 0.f, a1 = 0.f, a2 = 0.f, a3 = 0.f;
#pragma unroll
    for (int k = 0; k < 32; ++k) {
      float p0 = __uint_as_float(__builtin_amdgcn_readlane(__float_as_uint(h0), k));
      a0 += w[k] * p0;
      float p1 = __uint_as_float(__builtin_amdgcn_readlane(__float_as_uint(h0), k + 32));
      a1 += w[k + 32] * p1;
      float p2 = __uint_as_float(__builtin_amdgcn_readlane(__float_as_uint(h1), k));
      a2 += w[k + 64] * p2;
      float p3 = __uint_as_float(__builtin_amdgcn_readlane(__float_as_uint(h1), k + 32));
      a3 += w[k + 96] * p3;
    }
    zl[tid] = zv + (a0 + a1) + (a2 + a3);
    __syncthreads();
    int c = t * BATCH + b;
    if (tid < CELL) {
      float cand = ftanh(zl[tid]);
      float F = fsig(zl[CELL + tid]);
      float I = fsig(zl[2 * CELL + tid]);
      float O = fsig(zl[3 * CELL + tid]);
      C = F * C + I * cand;
      float H = ftanh(C) * O;
      Hl[tid] = H;
      Hbf[(size_t)c * CELL + tid] = f2bf(H);
      if (t == SEQ - 1) {
        outHC[(size_t)tid * BATCH + b] = H;
        outHC[(size_t)CELL * BATCH + (size_t)tid * BATCH + b] = C;
      }
    }
    __syncthreads();
  }
}

extern "C" void kernel_launch(void* const* d_in, const int* in_sizes, int n_in,
                              void* d_out, int out_size, void* d_ws, size_t ws_size,
                              hipStream_t stream) {
  const int*   x   = (const int*)d_in[0];
  const float* emb = (const float*)d_in[1];
  const float* Wc  = (const float*)d_in[2];
  const float* Bc  = (const float*)d_in[3];
  const float* Wf  = (const float*)d_in[4];
  const float* Bf  = (const float*)d_in[5];
  const float* Wi  = (const float*)d_in[6];
  const float* Bi  = (const float*)d_in[7];
  const float* Wo  = (const float*)d_in[8];
  const float* Bo  = (const float*)d_in[9];
  const float* W   = (const float*)d_in[10];
  const float* b   = (const float*)d_in[11];
  float* out = (float*)d_out;

  char* ws = (char*)d_ws;
  size_t off = 0;
  auto alloc = [&](size_t bytes) -> void* {
    void* p = ws + off;
    off = (off + bytes + 255) & ~(size_t)255;
    return p;
  };
  u16*   Wbf  = (u16*)  alloc((size_t)NPADV * EMB * 2);   // 2.56 MB
  float* bpad = (float*)alloc((size_t)NPADV * 4);         // 40 KB padded bias
  u16*   Wall = (u16*)  alloc((size_t)GATES * EMB * 2);   // 128 KB
  float* Ball = (float*)alloc((size_t)GATES * 4);         // 2 KB
  u16*   Xe   = (u16*)  alloc((size_t)ROWS * EMB * 2);    // 2 MB
  u16*   Hbf  = (u16*)  alloc((size_t)ROWS * CELL * 2);   // 2 MB
  float* Zin  = (float*)alloc((size_t)ROWS * GATES * 4);  // 16 MB

  hipLaunchKernelGGL(k_convert_W, dim3((NPADV * EMB + 255) / 256), dim3(256), 0, stream,
                     W, Wbf, b, bpad);
  hipLaunchKernelGGL(k_build_gates, dim3((GATES * EMB + 255) / 256), dim3(256), 0, stream,
                     Wc, Bc, Wf, Bf, Wi, Bi, Wo, Bo, Wall, Ball);
  hipLaunchKernelGGL(k_gather_xe, dim3((ROWS * EMB + 255) / 256), dim3(256), 0, stream,
                     x, emb, Xe);
  // Zin[c][r] = Xe[c]·Wall[r] + Ball[r]
  hipLaunchKernelGGL(k_gemm, dim3(GATES / 64, ROWS / 64), dim3(256), 0, stream,
                     Xe, Wall, Ball, Zin, GATES);
  // sequential recurrence, writes Hbf + final Ht/Ct
  hipLaunchKernelGGL(k_recur, dim3(BATCH), dim3(512), 0, stream,
                     Wc, Wf, Wi, Wo, Zin, Hbf, out + (size_t)ROWS * VOCAB);
  // out[c][v] = Hbf[c]·Wbf[v] + b[v]  (store-wait-decoupled batched stores)
  hipLaunchKernelGGL(k_vocab7, dim3(2048), dim3(256), 0, stream,
                     Hbf, Wbf, bpad, out);
}

// Round 12
// 331.550 us; speedup vs baseline: 1.3378x; 1.0282x over previous
//
#include <hip/hip_runtime.h>
#include <hip/hip_bf16.h>

#define SEQ   128
#define BATCH 64
#define EMB   128
#define CELL  128
#define VOCAB 10000
#define NPADV 10240          // vocab rows padded to /64
#define ROWS  8192           // SEQ*BATCH
#define GATES 512            // 4*CELL
#define INDIM 256            // EMB+CELL (gate weight row stride)
#define LSTRIDE 260          // LDS row stride (floats): 256 cols + 4 pad

typedef short  short8 __attribute__((ext_vector_type(8)));
typedef float  f32x4  __attribute__((ext_vector_type(4)));
typedef unsigned short u16;

static __device__ __forceinline__ u16 f2bf(float f) {
  union { float f; unsigned int u; } v; v.f = f;
  unsigned int u = v.u;
  return (u16)((u + 0x7fffu + ((u >> 16) & 1u)) >> 16);   // RNE
}
static __device__ __forceinline__ float fexp(float x) {
  return __builtin_amdgcn_exp2f(x * 1.44269504088896340736f);
}
static __device__ __forceinline__ float fsig(float x) {
  return __builtin_amdgcn_rcpf(1.0f + fexp(-x));
}
static __device__ __forceinline__ float ftanh(float x) {
  float e = fexp(2.0f * x);                 // e^(2x); overflows to inf -> returns 1 (ok)
  return 1.0f - 2.0f * __builtin_amdgcn_rcpf(e + 1.0f);
}

// ---------- prep kernels ----------
__global__ void k_convert_W(const float* __restrict__ W, u16* __restrict__ Wbf,
                            const float* __restrict__ b, float* __restrict__ bpad) {
  int idx = blockIdx.x * blockDim.x + threadIdx.x;
  if (idx < NPADV) bpad[idx] = (idx < VOCAB) ? b[idx] : 0.f;   // padded bias
  if (idx >= NPADV * EMB) return;
  int v = idx >> 7, k = idx & 127;
  float val = (v < VOCAB) ? W[(size_t)v * EMB + k] : 0.f;
  Wbf[idx] = f2bf(val);
}

__global__ void k_build_gates(const float* __restrict__ Wc, const float* __restrict__ Bc,
                              const float* __restrict__ Wf, const float* __restrict__ Bf,
                              const float* __restrict__ Wi, const float* __restrict__ Bi,
                              const float* __restrict__ Wo, const float* __restrict__ Bo,
                              u16* __restrict__ Wall, float* __restrict__ Ball) {
  int idx = blockIdx.x * blockDim.x + threadIdx.x;
  if (idx < GATES * EMB) {
    int r = idx >> 7, k = idx & 127;
    int g = r >> 7, j = r & 127;
    const float* Wg = (g == 0) ? Wc : (g == 1) ? Wf : (g == 2) ? Wi : Wo;
    Wall[idx] = f2bf(Wg[(size_t)j * INDIM + k]);          // embedding-part columns 0..127
  }
  if (idx < GATES) {
    int g = idx >> 7, j = idx & 127;
    const float* Bg = (g == 0) ? Bc : (g == 1) ? Bf : (g == 2) ? Bi : Bo;
    Ball[idx] = Bg[j];
  }
}

__global__ void k_gather_xe(const int* __restrict__ x, const float* __restrict__ emb,
                            u16* __restrict__ Xe) {
  int idx = blockIdx.x * blockDim.x + threadIdx.x;
  if (idx >= ROWS * EMB) return;
  int c = idx >> 7, e = idx & 127;
  int tok = x[c];                                         // x is [SEQ][BATCH], c = t*64+b
  Xe[idx] = f2bf(emb[(size_t)tok * EMB + e]);
}

// ---------- small bf16 MFMA GEMM (Zin): out[row][col] = A[row]·B[col] + bias[col] ----------
__launch_bounds__(256)
__global__ void k_gemm(const u16* __restrict__ A, const u16* __restrict__ B,
                       const float* __restrict__ bias, float* __restrict__ out,
                       int Nout) {
  __shared__ float tile[64][68];
  int lane = threadIdx.x & 63;
  int wave = threadIdx.x >> 6;
  int lr = lane & 15;
  int kh = lane >> 4;
  int rowbase = blockIdx.y * 64;
  int colblk  = blockIdx.x * 64;
  int colbase = colblk + wave * 16;

  const short8* A8 = (const short8*)A;
  const short8* B8 = (const short8*)B;

  f32x4 acc[4] = {};
#pragma unroll
  for (int ks = 0; ks < 4; ++ks) {
    short8 bfrag = B8[(size_t)(colbase + lr) * 16 + ks * 4 + kh];
#pragma unroll
    for (int m = 0; m < 4; ++m) {
      short8 afrag = A8[(size_t)(rowbase + m * 16 + lr) * 16 + ks * 4 + kh];
      acc[m] = __builtin_amdgcn_mfma_f32_16x16x32_bf16(afrag, bfrag, acc[m], 0, 0, 0);
    }
  }

#pragma unroll
  for (int m = 0; m < 4; ++m)
#pragma unroll
    for (int q = 0; q < 4; ++q)
      tile[m * 16 + kh * 4 + q][wave * 16 + lr] = acc[m][q];
  __syncthreads();

  int col4 = lane & 15;
  int c = colblk + col4 * 4;
  if (c < Nout) {
    f32x4 bv = {};
    if (bias) bv = *(const f32x4*)(bias + c);
#pragma unroll
    for (int i = 0; i < 4; ++i) {
      int r = wave * 16 + i * 4 + (lane >> 4);
      f32x4 v = *(const f32x4*)(&tile[r][col4 * 4]);
      v += bv;
      *(f32x4*)(out + (size_t)(rowbase + r) * Nout + c) = v;
    }
  }
}

// ---------- vocab projection v8: wave-local transpose, full-line burst stores ----------
// Probe data: v3's scatter pattern alone = 4.7 TB/s; 1KB full-line runs = ~6 TB/s;
// v3 kernel = 2.2 TB/s because each wave holds only ~2KB of stores in flight between
// load-waits (vmcnt FIFO: waiting on a load drains older stores). Fix: per 256-col
// panel, wave computes 16x256 via 64 MFMA, stages into its PRIVATE LDS patch (no
// barriers, waves disjoint), then bursts 16 x 1KB fully-contiguous row stores
// back-to-back -> 16KB in flight per wave (128KB/CU), full 128B lines.
__launch_bounds__(256, 2)
__global__ void k_vocab8(const u16* __restrict__ A, const u16* __restrict__ B,
                         const float* __restrict__ bpad, float* __restrict__ out) {
  extern __shared__ float lds[];                 // 4 waves x 16 x LSTRIDE floats
  int tid = threadIdx.x;
  int lane = tid & 63, wv = tid >> 6;            // 4 waves
  int lr = lane & 15, kh = lane >> 4;
  int band  = blockIdx.x >> 2;                   // 128 bands of 64 rows
  int slice = blockIdx.x & 3;                    // 4 col-slices of 2560
  int rowbase = band * 64 + wv * 16;             // wave owns 16 rows
  float* mylds = lds + wv * 16 * LSTRIDE;

  const short8* A8 = (const short8*)A;
  const short8* B8 = (const short8*)B;

  short8 af[4];
#pragma unroll
  for (int ks = 0; ks < 4; ++ks)
    af[ks] = A8[(size_t)(rowbase + lr) * 16 + ks * 4 + kh];

  for (int p = 0; p < 10; ++p) {                 // 10 panels of 256 cols
    int pb = slice * 2560 + p * 256;
    f32x4 bias_v = *(const f32x4*)(bpad + pb + lane * 4);  // reused by all 16 rows

#pragma unroll
    for (int bi = 0; bi < 4; ++bi) {             // 4 batches of 64 cols
      int cb = pb + bi * 64;
      short8 vf[4][4];
#pragma unroll
      for (int gi = 0; gi < 4; ++gi)
#pragma unroll
        for (int ks = 0; ks < 4; ++ks)
          vf[gi][ks] = B8[(size_t)(cb + gi * 16 + lr) * 16 + ks * 4 + kh];

      f32x4 acc0 = {}, acc1 = {}, acc2 = {}, acc3 = {};
#pragma unroll
      for (int ks = 0; ks < 4; ++ks) {           // 4 independent chains
        acc0 = __builtin_amdgcn_mfma_f32_16x16x32_bf16(vf[0][ks], af[ks], acc0, 0, 0, 0);
        acc1 = __builtin_amdgcn_mfma_f32_16x16x32_bf16(vf[1][ks], af[ks], acc1, 0, 0, 0);
        acc2 = __builtin_amdgcn_mfma_f32_16x16x32_bf16(vf[2][ks], af[ks], acc2, 0, 0, 0);
        acc3 = __builtin_amdgcn_mfma_f32_16x16x32_bf16(vf[3][ks], af[ks], acc3, 0, 0, 0);
      }
      // stage: lane holds row lr, cols cb + gi*16 + kh*4 .. +3
      float* wbase = mylds + lr * LSTRIDE + bi * 64 + kh * 4;
      *(f32x4*)(wbase +  0) = acc0;
      *(f32x4*)(wbase + 16) = acc1;
      *(f32x4*)(wbase + 32) = acc2;
      *(f32x4*)(wbase + 48) = acc3;
    }

    // burst store: 16 x 1KB fully-contiguous rows, back-to-back
    int c = pb + lane * 4;
    bool ok = c < VOCAB;                         // VOCAB%4==0: chunk fully valid or not
#pragma unroll
    for (int r = 0; r < 16; ++r) {
      f32x4 v = *(const f32x4*)(mylds + r * LSTRIDE + lane * 4);
      v += bias_v;
      if (ok)
        *(f32x4*)(out + (size_t)(rowbase + r) * VOCAB + c) = v;
    }
  }
}

// ---------- sequential LSTM recurrence: one workgroup per batch column ----------
__launch_bounds__(512, 2)
__global__ void k_recur(const float* __restrict__ Wc, const float* __restrict__ Wf,
                        const float* __restrict__ Wi, const float* __restrict__ Wo,
                        const float* __restrict__ Zin, u16* __restrict__ Hbf,
                        float* __restrict__ outHC) {
  __shared__ float Hl[CELL];
  __shared__ float zl[GATES];
  int tid = threadIdx.x;
  int b = blockIdx.x;
  int lane = tid & 63;
  int g = tid >> 7, j = tid & 127;
  const float* Wg = (g == 0) ? Wc : (g == 1) ? Wf : (g == 2) ? Wi : Wo;
  const float* wp = Wg + (size_t)j * INDIM + EMB;

  float w[128];
#pragma unroll
  for (int k = 0; k < 128; ++k) w[k] = wp[k];

  if (tid < CELL) Hl[tid] = 0.f;
  float C = 0.f;

  // rolling depth-2 Zin prefetch
  float zcur = Zin[(size_t)(0 * BATCH + b) * GATES + tid];
  float znxt = Zin[(size_t)(1 * BATCH + b) * GATES + tid];
  __syncthreads();

  for (int t = 0; t < SEQ; ++t) {
    float zv = zcur;
    zcur = znxt;
    if (t + 2 < SEQ)
      znxt = Zin[(size_t)((t + 2) * BATCH + b) * GATES + tid];

    float h0 = Hl[lane];
    float h1 = Hl[lane + 64];
    float a0 = 0.f, a1 = 0.f, a2 = 0.f, a3 = 0.f;
#pragma unroll
    for (int k = 0; k < 32; ++k) {
      float p0 = __uint_as_float(__builtin_amdgcn_readlane(__float_as_uint(h0), k));
      a0 += w[k] * p0;
      float p1 = __uint_as_float(__builtin_amdgcn_readlane(__float_as_uint(h0), k + 32));
      a1 += w[k + 32] * p1;
      float p2 = __uint_as_float(__builtin_amdgcn_readlane(__float_as_uint(h1), k));
      a2 += w[k + 64] * p2;
      float p3 = __uint_as_float(__builtin_amdgcn_readlane(__float_as_uint(h1), k + 32));
      a3 += w[k + 96] * p3;
    }
    zl[tid] = zv + (a0 + a1) + (a2 + a3);
    __syncthreads();
    int c = t * BATCH + b;
    if (tid < CELL) {
      float cand = ftanh(zl[tid]);
      float F = fsig(zl[CELL + tid]);
      float I = fsig(zl[2 * CELL + tid]);
      float O = fsig(zl[3 * CELL + tid]);
      C = F * C + I * cand;
      float H = ftanh(C) * O;
      Hl[tid] = H;
      Hbf[(size_t)c * CELL + tid] = f2bf(H);
      if (t == SEQ - 1) {
        outHC[(size_t)tid * BATCH + b] = H;
        outHC[(size_t)CELL * BATCH + (size_t)tid * BATCH + b] = C;
      }
    }
    __syncthreads();
  }
}

extern "C" void kernel_launch(void* const* d_in, const int* in_sizes, int n_in,
                              void* d_out, int out_size, void* d_ws, size_t ws_size,
                              hipStream_t stream) {
  const int*   x   = (const int*)d_in[0];
  const float* emb = (const float*)d_in[1];
  const float* Wc  = (const float*)d_in[2];
  const float* Bc  = (const float*)d_in[3];
  const float* Wf  = (const float*)d_in[4];
  const float* Bf  = (const float*)d_in[5];
  const float* Wi  = (const float*)d_in[6];
  const float* Bi  = (const float*)d_in[7];
  const float* Wo  = (const float*)d_in[8];
  const float* Bo  = (const float*)d_in[9];
  const float* W   = (const float*)d_in[10];
  const float* b   = (const float*)d_in[11];
  float* out = (float*)d_out;

  char* ws = (char*)d_ws;
  size_t off = 0;
  auto alloc = [&](size_t bytes) -> void* {
    void* p = ws + off;
    off = (off + bytes + 255) & ~(size_t)255;
    return p;
  };
  u16*   Wbf  = (u16*)  alloc((size_t)NPADV * EMB * 2);   // 2.56 MB
  float* bpad = (float*)alloc((size_t)NPADV * 4);         // 40 KB padded bias
  u16*   Wall = (u16*)  alloc((size_t)GATES * EMB * 2);   // 128 KB
  float* Ball = (float*)alloc((size_t)GATES * 4);         // 2 KB
  u16*   Xe   = (u16*)  alloc((size_t)ROWS * EMB * 2);    // 2 MB
  u16*   Hbf  = (u16*)  alloc((size_t)ROWS * CELL * 2);   // 2 MB
  float* Zin  = (float*)alloc((size_t)ROWS * GATES * 4);  // 16 MB

  hipLaunchKernelGGL(k_convert_W, dim3((NPADV * EMB + 255) / 256), dim3(256), 0, stream,
                     W, Wbf, b, bpad);
  hipLaunchKernelGGL(k_build_gates, dim3((GATES * EMB + 255) / 256), dim3(256), 0, stream,
                     Wc, Bc, Wf, Bf, Wi, Bi, Wo, Bo, Wall, Ball);
  hipLaunchKernelGGL(k_gather_xe, dim3((ROWS * EMB + 255) / 256), dim3(256), 0, stream,
                     x, emb, Xe);
  // Zin[c][r] = Xe[c]·Wall[r] + Ball[r]
  hipLaunchKernelGGL(k_gemm, dim3(GATES / 64, ROWS / 64), dim3(256), 0, stream,
                     Xe, Wall, Ball, Zin, GATES);
  // sequential recurrence, writes Hbf + final Ht/Ct
  hipLaunchKernelGGL(k_recur, dim3(BATCH), dim3(512), 0, stream,
                     Wc, Wf, Wi, Wo, Zin, Hbf, out + (size_t)ROWS * VOCAB);
  // out[c][v] = Hbf[c]·Wbf[v] + b[v]  (wave-local transpose, 1KB full-line bursts)
  hipLaunchKernelGGL(k_vocab8, dim3(512), dim3(256),
                     4 * 16 * LSTRIDE * sizeof(float), stream,
                     Hbf, Wbf, bpad, out);
}

// Round 13
// 328.707 us; speedup vs baseline: 1.3494x; 1.0086x over previous
//
#include <hip/hip_runtime.h>
#include <hip/hip_bf16.h>

#define SEQ   128
#define BATCH 64
#define EMB   128
#define CELL  128
#define VOCAB 10000
#define NPADV 10240          // vocab rows padded to /64
#define ROWS  8192           // SEQ*BATCH
#define GATES 512            // 4*CELL
#define INDIM 256            // EMB+CELL (gate weight row stride)

typedef short  short8 __attribute__((ext_vector_type(8)));
typedef float  f32x4  __attribute__((ext_vector_type(4)));
typedef unsigned short u16;

static __device__ __forceinline__ u16 f2bf(float f) {
  union { float f; unsigned int u; } v; v.f = f;
  unsigned int u = v.u;
  return (u16)((u + 0x7fffu + ((u >> 16) & 1u)) >> 16);   // RNE
}
static __device__ __forceinline__ float fexp(float x) {
  return __builtin_amdgcn_exp2f(x * 1.44269504088896340736f);
}
static __device__ __forceinline__ float fsig(float x) {
  return __builtin_amdgcn_rcpf(1.0f + fexp(-x));
}
static __device__ __forceinline__ float ftanh(float x) {
  float e = fexp(2.0f * x);                 // e^(2x); overflows to inf -> returns 1 (ok)
  return 1.0f - 2.0f * __builtin_amdgcn_rcpf(e + 1.0f);
}

// ---------- prep kernels ----------
__global__ void k_convert_W(const float* __restrict__ W, u16* __restrict__ Wbf,
                            const float* __restrict__ b, float* __restrict__ bpad) {
  int idx = blockIdx.x * blockDim.x + threadIdx.x;
  if (idx < NPADV) bpad[idx] = (idx < VOCAB) ? b[idx] : 0.f;   // padded bias
  if (idx >= NPADV * EMB) return;
  int v = idx >> 7, k = idx & 127;
  float val = (v < VOCAB) ? W[(size_t)v * EMB + k] : 0.f;
  Wbf[idx] = f2bf(val);
}

__global__ void k_build_gates(const float* __restrict__ Wc, const float* __restrict__ Bc,
                              const float* __restrict__ Wf, const float* __restrict__ Bf,
                              const float* __restrict__ Wi, const float* __restrict__ Bi,
                              const float* __restrict__ Wo, const float* __restrict__ Bo,
                              u16* __restrict__ Wall, float* __restrict__ Ball) {
  int idx = blockIdx.x * blockDim.x + threadIdx.x;
  if (idx < GATES * EMB) {
    int r = idx >> 7, k = idx & 127;
    int g = r >> 7, j = r & 127;
    const float* Wg = (g == 0) ? Wc : (g == 1) ? Wf : (g == 2) ? Wi : Wo;
    Wall[idx] = f2bf(Wg[(size_t)j * INDIM + k]);          // embedding-part columns 0..127
  }
  if (idx < GATES) {
    int g = idx >> 7, j = idx & 127;
    const float* Bg = (g == 0) ? Bc : (g == 1) ? Bf : (g == 2) ? Bi : Bo;
    Ball[idx] = Bg[j];
  }
}

__global__ void k_gather_xe(const int* __restrict__ x, const float* __restrict__ emb,
                            u16* __restrict__ Xe) {
  int idx = blockIdx.x * blockDim.x + threadIdx.x;
  if (idx >= ROWS * EMB) return;
  int c = idx >> 7, e = idx & 127;
  int tok = x[c];                                         // x is [SEQ][BATCH], c = t*64+b
  Xe[idx] = f2bf(emb[(size_t)tok * EMB + e]);
}

// ---------- small bf16 MFMA GEMM (Zin): out[row][col] = A[row]·B[col] + bias[col] ----------
__launch_bounds__(256)
__global__ void k_gemm(const u16* __restrict__ A, const u16* __restrict__ B,
                       const float* __restrict__ bias, float* __restrict__ out,
                       int Nout) {
  __shared__ float tile[64][68];
  int lane = threadIdx.x & 63;
  int wave = threadIdx.x >> 6;
  int lr = lane & 15;
  int kh = lane >> 4;
  int rowbase = blockIdx.y * 64;
  int colblk  = blockIdx.x * 64;
  int colbase = colblk + wave * 16;

  const short8* A8 = (const short8*)A;
  const short8* B8 = (const short8*)B;

  f32x4 acc[4] = {};
#pragma unroll
  for (int ks = 0; ks < 4; ++ks) {
    short8 bfrag = B8[(size_t)(colbase + lr) * 16 + ks * 4 + kh];
#pragma unroll
    for (int m = 0; m < 4; ++m) {
      short8 afrag = A8[(size_t)(rowbase + m * 16 + lr) * 16 + ks * 4 + kh];
      acc[m] = __builtin_amdgcn_mfma_f32_16x16x32_bf16(afrag, bfrag, acc[m], 0, 0, 0);
    }
  }

#pragma unroll
  for (int m = 0; m < 4; ++m)
#pragma unroll
    for (int q = 0; q < 4; ++q)
      tile[m * 16 + kh * 4 + q][wave * 16 + lr] = acc[m][q];
  __syncthreads();

  int col4 = lane & 15;
  int c = colblk + col4 * 4;
  if (c < Nout) {
    f32x4 bv = {};
    if (bias) bv = *(const f32x4*)(bias + c);
#pragma unroll
    for (int i = 0; i < 4; ++i) {
      int r = wave * 16 + i * 4 + (lane >> 4);
      f32x4 v = *(const f32x4*)(&tile[r][col4 * 4]);
      v += bv;
      *(f32x4*)(out + (size_t)(rowbase + r) * Nout + c) = v;
    }
  }
}

// ---------- vocab projection v9: v3 + prefetch depth 4 (store-ride pipeline) ----------
// Model (fits r1-r12): stores stay in flight only while every load-wait targets
// loads with all pending stores YOUNGER in the vmcnt FIFO. v3 (depth 1) lets a
// store ride 1 iteration (~2 in flight/wave -> 2.2 TB/s); raw store pattern alone
// = 4.7 TB/s (r10 probe). Depth-4 named buffers: phase order MFMA(vf_p) -> +bias
// -> LOAD(vf_p <- g+4) -> STORE(g); each store is younger than the loads waited on
// for the next 4 phases -> ~8 stores in flight/wave. All buffer indices static.
#define LOADG(VF, BV, G)                                                         \
  {                                                                              \
    int cg = colbase + (G) * 16;                                                 \
    _Pragma("unroll")                                                            \
    for (int ks = 0; ks < 4; ++ks)                                               \
      VF[ks] = B8[(size_t)(cg + lr) * 16 + ks * 4 + kh];                         \
    BV = *(const f32x4*)(bpad + cg + kh * 4);                                    \
  }

#define PHASE(VF, BV, G)                                                         \
  {                                                                              \
    f32x4 a0 = {}, a1 = {};                                                      \
    _Pragma("unroll")                                                            \
    for (int ks = 0; ks < 4; ++ks) {                                             \
      a0 = __builtin_amdgcn_mfma_f32_16x16x32_bf16(VF[ks], af0[ks], a0, 0, 0, 0);\
      a1 = __builtin_amdgcn_mfma_f32_16x16x32_bf16(VF[ks], af1[ks], a1, 0, 0, 0);\
    }                                                                            \
    a0 += BV;                                                                    \
    a1 += BV;                                                                    \
    if ((G) + 4 < 40) LOADG(VF, BV, (G) + 4)                                     \
    int colg = colbase + (G) * 16;                                               \
    if (colg < VOCAB) {                                                          \
      int c = colg + kh * 4;                                                     \
      *(f32x4*)(out + (size_t)(rowbase + lr) * VOCAB + c) = a0;                  \
      *(f32x4*)(out + (size_t)(rowbase + 16 + lr) * VOCAB + c) = a1;             \
    }                                                                            \
  }

__launch_bounds__(256, 4)
__global__ void k_vocab9(const u16* __restrict__ A, const u16* __restrict__ B,
                         const float* __restrict__ bpad, float* __restrict__ out) {
  int tid = threadIdx.x;
  int lane = tid & 63, wv = tid >> 6;
  int lr = lane & 15, kh = lane >> 4;
  int band  = blockIdx.x >> 2;            // 256 bands of 32 rows
  int slice = blockIdx.x & 3;             // 4 col-slices of 2560
  int rowbase = band * 32;
  int colbase = slice * 2560 + wv * 640;  // this wave: 40 groups of 16 cols

  const short8* A8 = (const short8*)A;
  const short8* B8 = (const short8*)B;

  short8 af0[4], af1[4];
#pragma unroll
  for (int ks = 0; ks < 4; ++ks) {
    af0[ks] = A8[(size_t)(rowbase + lr) * 16 + ks * 4 + kh];
    af1[ks] = A8[(size_t)(rowbase + 16 + lr) * 16 + ks * 4 + kh];
  }

  short8 vf0[4], vf1[4], vf2[4], vf3[4];
  f32x4 bv0, bv1, bv2, bv3;
  LOADG(vf0, bv0, 0)
  LOADG(vf1, bv1, 1)
  LOADG(vf2, bv2, 2)
  LOADG(vf3, bv3, 3)

  for (int gi = 0; gi < 10; ++gi) {
    int g = gi * 4;
    PHASE(vf0, bv0, g + 0)
    PHASE(vf1, bv1, g + 1)
    PHASE(vf2, bv2, g + 2)
    PHASE(vf3, bv3, g + 3)
  }
}

// ---------- sequential LSTM recurrence: one workgroup per batch column ----------
__launch_bounds__(512, 2)
__global__ void k_recur(const float* __restrict__ Wc, const float* __restrict__ Wf,
                        const float* __restrict__ Wi, const float* __restrict__ Wo,
                        const float* __restrict__ Zin, u16* __restrict__ Hbf,
                        float* __restrict__ outHC) {
  __shared__ float Hl[CELL];
  __shared__ float zl[GATES];
  int tid = threadIdx.x;
  int b = blockIdx.x;
  int lane = tid & 63;
  int g = tid >> 7, j = tid & 127;
  const float* Wg = (g == 0) ? Wc : (g == 1) ? Wf : (g == 2) ? Wi : Wo;
  const float* wp = Wg + (size_t)j * INDIM + EMB;

  float w[128];
#pragma unroll
  for (int k = 0; k < 128; ++k) w[k] = wp[k];

  if (tid < CELL) Hl[tid] = 0.f;
  float C = 0.f;

  // rolling depth-2 Zin prefetch
  float zcur = Zin[(size_t)(0 * BATCH + b) * GATES + tid];
  float znxt = Zin[(size_t)(1 * BATCH + b) * GATES + tid];
  __syncthreads();

  for (int t = 0; t < SEQ; ++t) {
    float zv = zcur;
    zcur = znxt;
    if (t + 2 < SEQ)
      znxt = Zin[(size_t)((t + 2) * BATCH + b) * GATES + tid];

    float h0 = Hl[lane];
    float h1 = Hl[lane + 64];
    float a0 = 0.f, a1 = 0.f, a2 = 0.f, a3 = 0.f;
#pragma unroll
    for (int k = 0; k < 32; ++k) {
      float p0 = __uint_as_float(__builtin_amdgcn_readlane(__float_as_uint(h0), k));
      a0 += w[k] * p0;
      float p1 = __uint_as_float(__builtin_amdgcn_readlane(__float_as_uint(h0), k + 32));
      a1 += w[k + 32] * p1;
      float p2 = __uint_as_float(__builtin_amdgcn_readlane(__float_as_uint(h1), k));
      a2 += w[k + 64] * p2;
      float p3 = __uint_as_float(__builtin_amdgcn_readlane(__float_as_uint(h1), k + 32));
      a3 += w[k + 96] * p3;
    }
    zl[tid] = zv + (a0 + a1) + (a2 + a3);
    __syncthreads();
    int c = t * BATCH + b;
    if (tid < CELL) {
      float cand = ftanh(zl[tid]);
      float F = fsig(zl[CELL + tid]);
      float I = fsig(zl[2 * CELL + tid]);
      float O = fsig(zl[3 * CELL + tid]);
      C = F * C + I * cand;
      float H = ftanh(C) * O;
      Hl[tid] = H;
      Hbf[(size_t)c * CELL + tid] = f2bf(H);
      if (t == SEQ - 1) {
        outHC[(size_t)tid * BATCH + b] = H;
        outHC[(size_t)CELL * BATCH + (size_t)tid * BATCH + b] = C;
      }
    }
    __syncthreads();
  }
}

extern "C" void kernel_launch(void* const* d_in, const int* in_sizes, int n_in,
                              void* d_out, int out_size, void* d_ws, size_t ws_size,
                              hipStream_t stream) {
  const int*   x   = (const int*)d_in[0];
  const float* emb = (const float*)d_in[1];
  const float* Wc  = (const float*)d_in[2];
  const float* Bc  = (const float*)d_in[3];
  const float* Wf  = (const float*)d_in[4];
  const float* Bf  = (const float*)d_in[5];
  const float* Wi  = (const float*)d_in[6];
  const float* Bi  = (const float*)d_in[7];
  const float* Wo  = (const float*)d_in[8];
  const float* Bo  = (const float*)d_in[9];
  const float* W   = (const float*)d_in[10];
  const float* b   = (const float*)d_in[11];
  float* out = (float*)d_out;

  char* ws = (char*)d_ws;
  size_t off = 0;
  auto alloc = [&](size_t bytes) -> void* {
    void* p = ws + off;
    off = (off + bytes + 255) & ~(size_t)255;
    return p;
  };
  u16*   Wbf  = (u16*)  alloc((size_t)NPADV * EMB * 2);   // 2.56 MB
  float* bpad = (float*)alloc((size_t)NPADV * 4);         // 40 KB padded bias
  u16*   Wall = (u16*)  alloc((size_t)GATES * EMB * 2);   // 128 KB
  float* Ball = (float*)alloc((size_t)GATES * 4);         // 2 KB
  u16*   Xe   = (u16*)  alloc((size_t)ROWS * EMB * 2);    // 2 MB
  u16*   Hbf  = (u16*)  alloc((size_t)ROWS * CELL * 2);   // 2 MB
  float* Zin  = (float*)alloc((size_t)ROWS * GATES * 4);  // 16 MB

  hipLaunchKernelGGL(k_convert_W, dim3((NPADV * EMB + 255) / 256), dim3(256), 0, stream,
                     W, Wbf, b, bpad);
  hipLaunchKernelGGL(k_build_gates, dim3((GATES * EMB + 255) / 256), dim3(256), 0, stream,
                     Wc, Bc, Wf, Bf, Wi, Bi, Wo, Bo, Wall, Ball);
  hipLaunchKernelGGL(k_gather_xe, dim3((ROWS * EMB + 255) / 256), dim3(256), 0, stream,
                     x, emb, Xe);
  // Zin[c][r] = Xe[c]·Wall[r] + Ball[r]
  hipLaunchKernelGGL(k_gemm, dim3(GATES / 64, ROWS / 64), dim3(256), 0, stream,
                     Xe, Wall, Ball, Zin, GATES);
  // sequential recurrence, writes Hbf + final Ht/Ct
  hipLaunchKernelGGL(k_recur, dim3(BATCH), dim3(512), 0, stream,
                     Wc, Wf, Wi, Wo, Zin, Hbf, out + (size_t)ROWS * VOCAB);
  // out[c][v] = Hbf[c]·Wbf[v] + b[v]  (depth-4 store-ride pipeline)
  hipLaunchKernelGGL(k_vocab9, dim3(1024), dim3(256), 0, stream,
                     Hbf, Wbf, bpad, out);
}